// Round 11
// baseline (983.109 us; speedup 1.0000x reference)
//
#include <hip/hip_runtime.h>
#include <math.h>

// Shapes: B=8, N=1024, D=64, H=4, DH=16, DI=128, DS=64, DTR=4, MAXP=512

__device__ __forceinline__ float wsum64(float v){
#pragma unroll
  for(int m=32;m>0;m>>=1) v += __shfl_xor(v, m, 64);
  return v;
}
__device__ __forceinline__ float wmax64(float v){
#pragma unroll
  for(int m=32;m>0;m>>=1) v = fmaxf(v, __shfl_xor(v, m, 64));
  return v;
}
__device__ __forceinline__ float silu_f(float x){ return x / (1.f + __expf(-x)); }

// ---------------------------------------------------------------------------
// K1: LN1 + Q / KV projection (wave per token). K,V packed float2, D-major:
// kvT[bh][dh][j] = (k,v). Fused prep: relT (blocks 0..64), c1wT (65..576).
__global__ __launch_bounds__(256) void k_ln1_qkv(
    const float* __restrict__ x, const float* __restrict__ w1, const float* __restrict__ b1,
    const float* __restrict__ Wq, const float* __restrict__ Wkv,
    const float* __restrict__ rel, const float* __restrict__ c1w,
    float* __restrict__ qb, float2* __restrict__ kvT,
    float* __restrict__ relT, float* __restrict__ c1wT){
  int lane = threadIdx.x & 63, warp = threadIdx.x >> 6;
  int token = blockIdx.x*4 + warp;            // 0..8191
  __shared__ float xt[4][64];
  float xv = x[(size_t)token*64 + lane];
  float mean = wsum64(xv) * 0.015625f;
  float dlt = xv - mean;
  float var = wsum64(dlt*dlt) * 0.015625f;
  float xn = dlt * rsqrtf(var + 1e-5f) * w1[lane] + b1[lane];
  xt[warp][lane] = xn;
  __syncthreads();
  float aq=0.f, ak=0.f, av=0.f;
#pragma unroll 4
  for(int dd=0; dd<64; ++dd){
    float xd = xt[warp][dd];
    aq += xd * Wq[dd*64 + lane];
    ak += xd * Wkv[dd*128 + lane];
    av += xd * Wkv[dd*128 + 64 + lane];
  }
  int b = token >> 10, i = token & 1023;
  int h = lane >> 4, dh = lane & 15;
  size_t o  = (((size_t)(b*4 + h))*1024 + i)*16 + dh;   // (B,H,N,DH) for q
  size_t oT = (((size_t)(b*4 + h))*16 + dh)*1024 + i;   // (B,H,DH,N) for k,v
  qb[o]=aq;
  kvT[oT] = make_float2(ak, av);

  if (blockIdx.x < 65){
    int idx = blockIdx.x*256 + threadIdx.x;   // over 16*1025
    if (idx < 16*1025){
      int c = idx / 1025;
      int d = idx - c*1025;
      relT[idx] = rel[d*16 + c];
    }
  } else if (blockIdx.x < 577){
    int idx = (blockIdx.x-65)*256 + threadIdx.x;   // over 131072
    int row = idx >> 9;
    int ii  = idx & 511;
    c1wT[idx] = c1w[(size_t)ii*256 + row];
  }
}

// ---------------------------------------------------------------------------
// K1b: Kmax[bh] = max_j ||k_j||_2 (softmax shift bound).
__global__ __launch_bounds__(256) void k_kmax(
    const float2* __restrict__ kvT, float* __restrict__ Kmax){
  int bh = blockIdx.x; int tid = threadIdx.x;
  const float2* base = kvT + (size_t)bh*16*1024;
  float mx = 0.f;
#pragma unroll
  for(int r=0;r<4;++r){
    int j = tid + 256*r;
    float ss = 0.f;
#pragma unroll
    for(int c=0;c<16;++c){ float2 kv = base[c*1024 + j]; ss += kv.x*kv.x; }
    mx = fmaxf(mx, ss);
  }
  mx = wmax64(mx);
  __shared__ float red[4];
  int lane = tid&63, wv = tid>>6;
  if(lane==0) red[wv]=mx;
  __syncthreads();
  if(tid==0) Kmax[bh] = sqrtf(fmaxf(fmaxf(red[0],red[1]),fmaxf(red[2],red[3])));
}

// ---------------------------------------------------------------------------
// K2: attention. Bound-shift softmax (exact). Gc via inverse dist map.
// Main loop: 2-stage REGISTER PIPELINE (kvA/kvB double buffer) so each
// step's kv/mask loads overlap the previous step's VALU.
#define ATTN_STEP(KV, MKA, MKB, J) do {                                       \
    float sv0 = Gc[r0][(J)], sv1 = Gc[r1][(J)];                               \
    _Pragma("unroll")                                                         \
    for(int c=0;c<16;++c){ sv0 += q0[c]*KV[c].x; sv1 += q1[c]*KV[c].x; }      \
    float p0 = (MKA) ? 0.f : __expf(sv0 - M0);                                \
    float p1 = (MKB) ? 0.f : __expf(sv1 - M1);                                \
    s0 += p0; s1 += p1;                                                       \
    _Pragma("unroll")                                                         \
    for(int c=0;c<16;++c){ a0[c] += p0*KV[c].y; a1[c] += p1*KV[c].y; }        \
  } while(0)

__global__ __launch_bounds__(256, 3) void k_attn(
    const float* __restrict__ qb, const float2* __restrict__ kvT,
    const int* __restrict__ dmask, const float* __restrict__ relT,
    const float* __restrict__ Kmax, float* __restrict__ attn_raw){
  int tid = threadIdx.x;
  int lane = tid & 63, wv = tid >> 6;       // wave 0..3
  int bh  = blockIdx.y;                     // 0..31
  int i0  = blockIdx.x*8;                   // grid.x = 128
  int b = bh >> 2, h = bh & 3;
  int r0 = wv*2, r1 = wv*2 + 1;

  __shared__ float Gc[8][1024];      // 32 KB; aliased as red[] in epilogue
  __shared__ float qs[8][16];
  __shared__ float G0s[8], G1024s[8];
  __shared__ float gmS[8];
  __shared__ float Ms[8];
  __shared__ float sums[8];

  if (tid < 128){
    int r = tid >> 4, c = tid & 15;
    qs[r][c] = qb[((size_t)bh*1024 + i0 + r)*16 + c] * 0.25f;
  }
  __syncthreads();

  // --- phase 1: interior Gc via inverse map (lane owns d) ---
#pragma unroll 1
  for(int bb=0; bb<5; ++bb){
    int d = tid + 256*bb;
    if (d <= 1024){
      float rl[16];
#pragma unroll
      for(int c=0;c<16;++c) rl[c] = relT[c*1025 + d];
#pragma unroll
      for(int r=0;r<8;++r){
        float g = 0.f;
#pragma unroll
        for(int c=0;c<16;++c) g += qs[r][c]*rl[c];
        if (d == 0)        G0s[r] = g;
        else if (d == 1024) G1024s[r] = g;
        else {
          int j = i0 + r + 512 - d;
          if (j >= 0 && j < 1024) Gc[r][j] = g;
        }
      }
    }
  }
  __syncthreads();
  // --- phase 2: clip-plateau tails ---
#pragma unroll
  for(int r=0;r<8;++r){
    float g0 = G0s[r], g1 = G1024s[r];
    int lo = i0 + r - 512;     // j <= lo  -> dist clipped high (d=1024)
    int hi = i0 + r + 512;     // j >= hi  -> dist clipped low  (d=0)
#pragma unroll
    for(int p=0;p<4;++p){
      int j = tid + 256*p;
      if (j >= hi) Gc[r][j] = g0;
      else if (j <= lo) Gc[r][j] = g1;
    }
  }
  __syncthreads();
  // --- phase 3: row max of Gc ---
  {
    int r = tid >> 5, jb = tid & 31;
    float gm = -3.0e38f;
#pragma unroll
    for(int k=0;k<32;++k) gm = fmaxf(gm, Gc[r][jb + 32*k]);
#pragma unroll
    for(int m=1;m<32;m<<=1) gm = fmaxf(gm, __shfl_xor(gm, m, 64));
    if ((lane&31)==0) gmS[r] = gm;
  }
  __syncthreads();
  if (tid < 8){
    float qn = 0.f;
#pragma unroll
    for(int c=0;c<16;++c) qn += qs[tid][c]*qs[tid][c];
    Ms[tid] = gmS[tid] + sqrtf(qn)*Kmax[bh];
  }
  __syncthreads();

  float q0[16], q1[16];
#pragma unroll
  for(int c=0;c<16;++c){ q0[c]=qs[r0][c]; q1[c]=qs[r1][c]; }
  float M0 = Ms[r0], M1 = Ms[r1];

  const float2* kvb = kvT + (size_t)bh*16*1024;
  const int* mb0 = dmask + ((size_t)bh*1024 + i0 + r0)*1024;
  const int* mb1 = dmask + ((size_t)bh*1024 + i0 + r1)*1024;

  float s0=0.f, s1=0.f;
  float a0[16], a1[16];
#pragma unroll
  for(int c=0;c<16;++c){ a0[c]=0.f; a1[c]=0.f; }

  // --- pipelined main loop: compute buffer A while loading buffer B ---
  float2 kvA[16], kvB[16];
  int mkA0, mkA1, mkB0, mkB1;
  {
    int j = lane;
#pragma unroll
    for(int c=0;c<16;++c) kvA[c] = kvb[c*1024 + j];
    mkA0 = mb0[j]; mkA1 = mb1[j];
  }
#pragma unroll 1
  for(int tt=0; tt<8; ++tt){
    int jA = lane + 128*tt;
    int jB = jA + 64;
#pragma unroll
    for(int c=0;c<16;++c) kvB[c] = kvb[c*1024 + jB];
    mkB0 = mb0[jB]; mkB1 = mb1[jB];
    ATTN_STEP(kvA, mkA0, mkA1, jA);
    if (tt < 7){
      int jN = jA + 128;
#pragma unroll
      for(int c=0;c<16;++c) kvA[c] = kvb[c*1024 + jN];
      mkA0 = mb0[jN]; mkA1 = mb1[jN];
    }
    ATTN_STEP(kvB, mkB0, mkB1, jB);
  }
  // uniform shift per row -> plain reductions
  s0 = wsum64(s0); s1 = wsum64(s1);
#pragma unroll
  for(int c=0;c<16;++c){
    float x0 = a0[c];
    x0 += __shfl_xor(x0, 32, 64); x0 += __shfl_xor(x0, 16, 64);
    a0[c] = x0;
    float x1 = a1[c];
    x1 += __shfl_xor(x1, 32, 64); x1 += __shfl_xor(x1, 16, 64);
    a1[c] = x1;
  }
  __syncthreads();            // all waves done with Gc -> safe to alias
  float* red = &Gc[0][0];     // red[row*272 + g*17 + c]
  if (lane < 16){
#pragma unroll
    for(int c=0;c<16;++c){
      red[r0*272 + lane*17 + c] = a0[c];
      red[r1*272 + lane*17 + c] = a1[c];
    }
  }
  if (lane == 0){ sums[r0] = s0; sums[r1] = s1; }
  __syncthreads();
  if (tid < 128){
    int row = tid >> 4, c = tid & 15;
    float tot = 0.f;
#pragma unroll
    for(int g=0; g<16; ++g) tot += red[row*272 + g*17 + c];
    attn_raw[((size_t)b*1024 + i0 + row)*64 + h*16 + c] = tot / sums[row];
  }
}

// ---------------------------------------------------------------------------
// K3: Wo proj + double residual + LN2 + W_in (u0, silu(z)). wave per token.
__global__ __launch_bounds__(256) void k_post_attn(
    const float* __restrict__ x, const float* __restrict__ attn_raw,
    const float* __restrict__ Wo, const float* __restrict__ bo,
    const float* __restrict__ ln2w, const float* __restrict__ ln2b,
    const float* __restrict__ W_in,
    float* __restrict__ x2, float* __restrict__ u0, float* __restrict__ zsarr){
  int lane = threadIdx.x & 63, warp = threadIdx.x >> 6;
  int token = blockIdx.x*4 + warp;
  __shared__ float ar[4][64];
  __shared__ float lnv[4][64];
  ar[warp][lane] = attn_raw[(size_t)token*64 + lane];
  __syncthreads();
  float acc = bo[lane];
#pragma unroll 4
  for(int dd=0;dd<64;++dd) acc += ar[warp][dd]*Wo[dd*64+lane];
  float t = 2.f*x[(size_t)token*64+lane] + acc;    // x + (attn_out + x)
  x2[(size_t)token*64+lane] = t;
  float mean = wsum64(t)*0.015625f;
  float dlt = t-mean;
  float var = wsum64(dlt*dlt)*0.015625f;
  float ln = dlt*rsqrtf(var+1e-5f)*ln2w[lane]+ln2b[lane];
  lnv[warp][lane]=ln;
  __syncthreads();
  float a0=0.f,a1=0.f,a2=0.f,a3=0.f;
#pragma unroll 4
  for(int dd=0;dd<64;++dd){
    float xd = lnv[warp][dd];
    const float* wr = W_in + dd*256;
    a0 += xd*wr[lane]; a1 += xd*wr[lane+64]; a2 += xd*wr[lane+128]; a3 += xd*wr[lane+192];
  }
  u0[(size_t)token*128 + lane] = a0;
  u0[(size_t)token*128 + 64 + lane] = a1;
  zsarr[(size_t)token*128 + lane] = silu_f(a2);
  zsarr[(size_t)token*128 + 64 + lane] = silu_f(a3);
}

// ---------------------------------------------------------------------------
// K4: causal depthwise conv4 + silu + x-proj(132) + softplus dt. 128 lanes/token.
__global__ __launch_bounds__(256) void k_conv_proj(
    const float* __restrict__ u0, const float* __restrict__ conv_w, const float* __restrict__ conv_b,
    const float* __restrict__ W_xproj, const float* __restrict__ W_dt, const float* __restrict__ b_dt,
    float* __restrict__ uarr, float* __restrict__ Bmp, float* __restrict__ Cmp, float* __restrict__ dtarr){
  int sub = threadIdx.x >> 7, c = threadIdx.x & 127;
  int token = blockIdx.x*2 + sub;
  int b = token >> 10, i = token & 1023;
  __shared__ float us[2][128];
  __shared__ float dtin[2][4];
  float acc = conv_b[c];
#pragma unroll
  for(int k2=0;k2<4;++k2){
    int t2 = i - 3 + k2;
    if (t2 >= 0) acc += u0[((size_t)b*1024 + t2)*128 + c]*conv_w[c*4+k2];
  }
  float uv = silu_f(acc);
  uarr[(size_t)token*128 + c] = uv;
  us[sub][c] = uv;
  __syncthreads();
  float accA = 0.f, accB = 0.f;
  int cB = 128 + (c & 3);
#pragma unroll 4
  for(int dd=0; dd<128; ++dd){
    float xd = us[sub][dd];
    accA += xd * W_xproj[dd*132 + c];
    accB += xd * W_xproj[dd*132 + cB];
  }
  if (c < 4){ dtin[sub][c] = accA; Cmp[(size_t)token*64 + 60 + c] = accB; }
  else if (c < 68) Bmp[(size_t)token*64 + (c-4)] = accA;
  else             Cmp[(size_t)token*64 + (c-68)] = accA;
  __syncthreads();
  float dv = b_dt[c];
#pragma unroll
  for(int r2=0;r2<4;++r2) dv += dtin[sub][r2]*W_dt[r2*128 + c];
  dv = fmaxf(dv, 0.f) + log1pf(expf(-fabsf(dv)));   // softplus, stable
  dtarr[(size_t)token*128 + c] = dv;
}

// ---------------------------------------------------------------------------
// K5a: chunked scan phase A. wave = (b,d,chunk); lane = s. Per-chunk
// P = exp(A*sum dt) and R (zero-start response). 8192 waves -> 8/SIMD.
__global__ __launch_bounds__(256) void k_scan_a(
    const float* __restrict__ dtarr, const float* __restrict__ uarr,
    const float* __restrict__ Bmp, const float* __restrict__ A_log,
    float* __restrict__ Parr, float* __restrict__ Rarr){
  int lane = threadIdx.x & 63, warp = threadIdx.x >> 6;
  int w = blockIdx.x*4 + warp;          // 0..8191
  int c = w & 7, d = (w >> 3) & 127, b = w >> 10;
  float A = -expf(A_log[d*64 + lane]);
  int tb = c*128;
  const float* dtp = dtarr + ((size_t)b*1024 + tb)*128 + d;
  const float* up  = uarr  + ((size_t)b*1024 + tb)*128 + d;
  const float* Bp  = Bmp   + ((size_t)b*1024 + tb)*64 + lane;
  float R = 0.f, sdt = 0.f;
  for(int t0=0; t0<128; t0+=8){
    float dtc[8], uc[8], Bc[8];
#pragma unroll
    for(int r=0;r<8;++r){
      dtc[r]=dtp[(size_t)(t0+r)*128]; uc[r]=up[(size_t)(t0+r)*128]; Bc[r]=Bp[(size_t)(t0+r)*64];
    }
#pragma unroll
    for(int r=0;r<8;++r){
      float dt = dtc[r];
      R = R*__expf(dt*A) + dt*uc[r]*Bc[r];
      sdt += dt;
    }
  }
  Parr[(size_t)w*64 + lane] = __expf(sdt*A);
  Rarr[(size_t)w*64 + lane] = R;
}

// ---------------------------------------------------------------------------
// K5b: chunked scan phase C. Compose h_start from prior chunk summaries,
// then replay chunk emitting y (8 ILP wave reductions).
__global__ __launch_bounds__(256) void k_scan_c(
    const float* __restrict__ dtarr, const float* __restrict__ uarr,
    const float* __restrict__ Bmp, const float* __restrict__ Cmp,
    const float* __restrict__ zsarr, const float* __restrict__ A_log,
    const float* __restrict__ Dm, const float* __restrict__ Parr,
    const float* __restrict__ Rarr, float* __restrict__ ymp){
  int lane = threadIdx.x & 63, warp = threadIdx.x >> 6;
  int w = blockIdx.x*4 + warp;          // 0..8191
  int c = w & 7, d = (w >> 3) & 127, b = w >> 10;
  float A = -expf(A_log[d*64 + lane]);
  float Dv = Dm[d];
  float h = 0.f;
  int wbase = w - c;
#pragma unroll 1
  for(int cp=0; cp<c; ++cp){
    float P = Parr[(size_t)(wbase+cp)*64 + lane];
    float R = Rarr[(size_t)(wbase+cp)*64 + lane];
    h = h*P + R;
  }
  int tb = c*128;
  const float* dtp = dtarr + ((size_t)b*1024 + tb)*128 + d;
  const float* up  = uarr  + ((size_t)b*1024 + tb)*128 + d;
  const float* zp  = zsarr + ((size_t)b*1024 + tb)*128 + d;
  const float* Bp  = Bmp   + ((size_t)b*1024 + tb)*64 + lane;
  const float* Cp  = Cmp   + ((size_t)b*1024 + tb)*64 + lane;
  float* yp        = ymp   + ((size_t)b*1024 + tb)*128 + d;
  for(int t0=0; t0<128; t0+=8){
    float dtc[8], uc[8], Bc[8], Cc[8], zc[8];
#pragma unroll
    for(int r=0;r<8;++r){
      dtc[r]=dtp[(size_t)(t0+r)*128]; uc[r]=up[(size_t)(t0+r)*128];
      Bc[r]=Bp[(size_t)(t0+r)*64];    Cc[r]=Cp[(size_t)(t0+r)*64];
      zc[r]=zp[(size_t)(t0+r)*128];
    }
    float hc[8];
#pragma unroll
    for(int r=0;r<8;++r){
      float dt = dtc[r];
      h = h*__expf(dt*A) + dt*uc[r]*Bc[r];
      hc[r] = h*Cc[r];
    }
    float y[8];
#pragma unroll
    for(int r=0;r<8;++r) y[r] = wsum64(hc[r]);
    if (lane==0){
#pragma unroll
      for(int r=0;r<8;++r) yp[(size_t)(t0+r)*128] = (y[r] + uc[r]*Dv)*zc[r];
    }
  }
}

// ---------------------------------------------------------------------------
// K6: y @ W_out + leaky + group(4)-RMS-norm. wave per token.
__global__ __launch_bounds__(256) void k_wout(
    const float* __restrict__ ymp, const float* __restrict__ W_out,
    const float* __restrict__ gamma, float* __restrict__ marr){
  int lane = threadIdx.x & 63, warp = threadIdx.x >> 6;
  int token = blockIdx.x*4 + warp;
  __shared__ float ys[4][128];
  ys[warp][lane]      = ymp[(size_t)token*128 + lane];
  ys[warp][lane+64]   = ymp[(size_t)token*128 + 64 + lane];
  __syncthreads();
  float acc = 0.f;
#pragma unroll 4
  for(int dd=0; dd<128; ++dd) acc += ys[warp][dd]*W_out[dd*64 + lane];
  acc = acc >= 0.f ? acc : 0.01f*acc;                 // leaky relu
  float ss = acc*acc;
#pragma unroll
  for(int m=1;m<16;m<<=1) ss += __shfl_xor(ss, m, 64); // 16-lane group sum
  float rms = sqrtf(ss)*0.25f;                         // * dpg^-0.5 (dpg=16)
  marr[(size_t)token*64 + lane] = acc/(rms + 1e-5f)*gamma[lane];
}

// ---------------------------------------------------------------------------
// K7: GLU conv1 -> h2[b, tau(0..1026), i(0..255)], tau-major. Weights read
// from c1wT (lane-contiguous dwords).
__global__ __launch_bounds__(256) void k_h2(
    const float* __restrict__ marr, const float* __restrict__ c1wT,
    const float* __restrict__ c1b, float* __restrict__ h2){
  int b = blockIdx.y;
  int t0 = blockIdx.x * 16;
  int tid = threadIdx.x;
  __shared__ float ms[19][64];
  for(int l = tid; l < 19*64; l += 256){
    int row = l >> 6, cc = l & 63;
    int t = t0 - 3 + row;
    ms[row][cc] = (t >= 0 && t < 1024) ? marr[((size_t)b*1024 + t)*64 + cc] : 0.f;
  }
  __syncthreads();
  int i = tid;
  float acc1[16], acc2[16];
#pragma unroll
  for(int tl=0;tl<16;++tl){ acc1[tl]=0.f; acc2[tl]=0.f; }
  for(int cc=0; cc<64; ++cc){
    float mv[19];
#pragma unroll
    for(int r2=0;r2<19;++r2) mv[r2] = ms[r2][cc];
    const float* wr = c1wT + (size_t)cc*4*512;
    float wa0 = wr[      i], wa1 = wr[ 512+i], wa2 = wr[1024+i], wa3 = wr[1536+i];
    float wg0 = wr[  256+i], wg1 = wr[ 768+i], wg2 = wr[1280+i], wg3 = wr[1792+i];
#pragma unroll
    for(int tl=0; tl<16; ++tl){
      acc1[tl] += wa0*mv[tl+0] + wa1*mv[tl+1] + wa2*mv[tl+2] + wa3*mv[tl+3];
      acc2[tl] += wg0*mv[tl+0] + wg1*mv[tl+1] + wg2*mv[tl+2] + wg3*mv[tl+3];
    }
  }
  float bb1 = c1b[i], bb2 = c1b[i+256];
#pragma unroll
  for(int tl=0; tl<16; ++tl){
    int t = t0 + tl;
    if (t < 1027){
      float o1 = acc1[tl] + bb1;
      float o2 = acc2[tl] + bb2;
      h2[((size_t)b*1027 + t)*256 + i] = o1 * silu_f(o2);
    }
  }
}

// ---------------------------------------------------------------------------
// K8: conv2 (flipped d1_w) + 0.5*ff + residuals + LN3 -> out.
// 16 tokens per block: d1w streamed ONCE per block (256KB).
__global__ __launch_bounds__(256) void k_ff_final(
    const float* __restrict__ h2, const float* __restrict__ d1w, const float* __restrict__ d1b,
    const float* __restrict__ x2, const float* __restrict__ marr,
    const float* __restrict__ ln3w, const float* __restrict__ ln3b,
    float* __restrict__ out){
  int b = blockIdx.y;
  int s0 = blockIdx.x * 16;      // grid.x = 64
  int tid = threadIdx.x;
  int o = tid & 63, sg = tid >> 6;
  __shared__ float hs[19][256];
  for(int l = tid; l < 19*256; l += 256){
    int row = l >> 8, cc = l & 255;
    hs[row][cc] = h2[((size_t)b*1027 + s0 + row)*256 + cc];
  }
  __syncthreads();
  int sl = sg*4;
  float acc0=0.f, acc1=0.f, acc2=0.f, acc3=0.f;
  const float4* wb = (const float4*)d1w + o;   // d1w[i][o][0..3], lane-contig
#pragma unroll 2
  for(int i2=0; i2<256; ++i2){
    float4 wv = wb[(size_t)i2*64];
    float h0=hs[sl+0][i2], h1=hs[sl+1][i2], h2v=hs[sl+2][i2], h3=hs[sl+3][i2];
    float h4=hs[sl+4][i2], h5=hs[sl+5][i2], h6=hs[sl+6][i2];
    acc0 += h0*wv.w + h1*wv.z + h2v*wv.y + h3*wv.x;
    acc1 += h1*wv.w + h2v*wv.z + h3*wv.y + h4*wv.x;
    acc2 += h2v*wv.w + h3*wv.z + h4*wv.y + h5*wv.x;
    acc3 += h3*wv.w + h4*wv.z + h5*wv.y + h6*wv.x;
  }
  float accs[4] = {acc0, acc1, acc2, acc3};
  float bo_ = d1b[o];
#pragma unroll
  for(int r=0;r<4;++r){
    int s = s0 + sl + r;
    size_t idx = ((size_t)b*1024 + s)*64 + o;
    float tot = x2[idx] + marr[idx] + 0.5f*(accs[r] + bo_);
    float mean = wsum64(tot)*0.015625f;
    float dlt = tot - mean;
    float var = wsum64(dlt*dlt)*0.015625f;
    out[idx] = dlt*rsqrtf(var+1e-5f)*ln3w[o] + ln3b[o];
  }
}

// ---------------------------------------------------------------------------
extern "C" void kernel_launch(void* const* d_in, const int* in_sizes, int n_in,
                              void* d_out, int out_size, void* d_ws, size_t ws_size,
                              hipStream_t stream){
  const float* x       = (const float*)d_in[0];
  const int*   dmask   = (const int*)  d_in[1];   // bool -> int32 per harness
  const float* ln1w    = (const float*)d_in[2];
  const float* ln1b    = (const float*)d_in[3];
  const float* Wq      = (const float*)d_in[4];
  const float* Wkv     = (const float*)d_in[5];
  const float* Wo      = (const float*)d_in[6];
  const float* bo      = (const float*)d_in[7];
  const float* rel     = (const float*)d_in[8];
  const float* ln2w    = (const float*)d_in[9];
  const float* ln2b    = (const float*)d_in[10];
  const float* W_in    = (const float*)d_in[11];
  const float* conv_w  = (const float*)d_in[12];
  const float* conv_b  = (const float*)d_in[13];
  const float* W_xproj = (const float*)d_in[14];
  const float* W_dt    = (const float*)d_in[15];
  const float* b_dt    = (const float*)d_in[16];
  const float* A_log   = (const float*)d_in[17];
  const float* Dm      = (const float*)d_in[18];
  const float* W_out   = (const float*)d_in[19];
  const float* gamma   = (const float*)d_in[20];
  const float* c1w     = (const float*)d_in[21];
  const float* c1b     = (const float*)d_in[22];
  const float* d1w     = (const float*)d_in[23];
  const float* d1b     = (const float*)d_in[24];
  const float* ln3w    = (const float*)d_in[25];
  const float* ln3b    = (const float*)d_in[26];
  float* outp = (float*)d_out;

  float* ws = (float*)d_ws;
  float* qb       = ws;              // 524288
  float* kvT      = qb      + 524288;   // 1048576 floats (float2 view)
  float* attn_raw = kvT     + 1048576;  // 524288
  float* x2       = attn_raw+ 524288;
  float* u0       = x2      + 524288;   // 1048576
  float* zsarr    = u0      + 1048576;
  float* uarr     = zsarr   + 1048576;
  float* dtarr    = uarr    + 1048576;
  float* Bmp      = dtarr   + 1048576;  // 524288
  float* Cmp      = Bmp     + 524288;
  float* ymp      = Cmp     + 524288;   // 1048576
  float* marr     = ymp     + 1048576;  // 524288
  float* h2       = marr    + 524288;   // 2103296
  float* relT     = h2      + 2103296;  // 16400
  float* c1wT     = relT    + 16400;    // 131072
  float* Parr     = c1wT    + 131072;   // 524288
  float* Rarr     = Parr    + 524288;   // 524288
  float* Kmaxa    = Rarr    + 524288;   // 32

  k_ln1_qkv  <<<2048, 256, 0, stream>>>(x, ln1w, ln1b, Wq, Wkv, rel, c1w,
                                        qb, (float2*)kvT, relT, c1wT);
  k_kmax     <<<32, 256, 0, stream>>>((const float2*)kvT, Kmaxa);
  k_attn     <<<dim3(128,32), 256, 0, stream>>>(qb, (const float2*)kvT, dmask, relT, Kmaxa, attn_raw);
  k_post_attn<<<2048, 256, 0, stream>>>(x, attn_raw, Wo, bo, ln2w, ln2b, W_in, x2, u0, zsarr);
  k_conv_proj<<<4096, 256, 0, stream>>>(u0, conv_w, conv_b, W_xproj, W_dt, b_dt, uarr, Bmp, Cmp, dtarr);
  k_scan_a   <<<2048, 256, 0, stream>>>(dtarr, uarr, Bmp, A_log, Parr, Rarr);
  k_scan_c   <<<2048, 256, 0, stream>>>(dtarr, uarr, Bmp, Cmp, zsarr, A_log, Dm, Parr, Rarr, ymp);
  k_wout     <<<2048, 256, 0, stream>>>(ymp, W_out, gamma, marr);
  k_h2       <<<dim3(65,8), 256, 0, stream>>>(marr, c1wT, c1b, h2);
  k_ff_final <<<dim3(64,8), 256, 0, stream>>>(h2, d1w, d1b, x2, marr, ln3w, ln3b, outp);
}

// Round 12
// 737.125 us; speedup vs baseline: 1.3337x; 1.3337x over previous
//
#include <hip/hip_runtime.h>
#include <math.h>

// Shapes: B=8, N=1024, D=64, H=4, DH=16, DI=128, DS=64, DTR=4, MAXP=512

__device__ __forceinline__ float wsum64(float v){
#pragma unroll
  for(int m=32;m>0;m>>=1) v += __shfl_xor(v, m, 64);
  return v;
}
__device__ __forceinline__ float wmax64(float v){
#pragma unroll
  for(int m=32;m>0;m>>=1) v = fmaxf(v, __shfl_xor(v, m, 64));
  return v;
}
__device__ __forceinline__ float silu_f(float x){ return x / (1.f + __expf(-x)); }

// ---------------------------------------------------------------------------
// K1: LN1 + Q / KV projection (wave per token). K,V packed float2, D-major:
// kvT[bh][dh][j] = (k,v). Fused prep: relT (blocks 0..64), c1wT (65..576).
__global__ __launch_bounds__(256) void k_ln1_qkv(
    const float* __restrict__ x, const float* __restrict__ w1, const float* __restrict__ b1,
    const float* __restrict__ Wq, const float* __restrict__ Wkv,
    const float* __restrict__ rel, const float* __restrict__ c1w,
    float* __restrict__ qb, float2* __restrict__ kvT,
    float* __restrict__ relT, float* __restrict__ c1wT){
  int lane = threadIdx.x & 63, warp = threadIdx.x >> 6;
  int token = blockIdx.x*4 + warp;            // 0..8191
  __shared__ float xt[4][64];
  float xv = x[(size_t)token*64 + lane];
  float mean = wsum64(xv) * 0.015625f;
  float dlt = xv - mean;
  float var = wsum64(dlt*dlt) * 0.015625f;
  float xn = dlt * rsqrtf(var + 1e-5f) * w1[lane] + b1[lane];
  xt[warp][lane] = xn;
  __syncthreads();
  float aq=0.f, ak=0.f, av=0.f;
#pragma unroll 4
  for(int dd=0; dd<64; ++dd){
    float xd = xt[warp][dd];
    aq += xd * Wq[dd*64 + lane];
    ak += xd * Wkv[dd*128 + lane];
    av += xd * Wkv[dd*128 + 64 + lane];
  }
  int b = token >> 10, i = token & 1023;
  int h = lane >> 4, dh = lane & 15;
  size_t o  = (((size_t)(b*4 + h))*1024 + i)*16 + dh;   // (B,H,N,DH) for q
  size_t oT = (((size_t)(b*4 + h))*16 + dh)*1024 + i;   // (B,H,DH,N) for k,v
  qb[o]=aq;
  kvT[oT] = make_float2(ak, av);

  if (blockIdx.x < 65){
    int idx = blockIdx.x*256 + threadIdx.x;   // over 16*1025
    if (idx < 16*1025){
      int c = idx / 1025;
      int d = idx - c*1025;
      relT[idx] = rel[d*16 + c];
    }
  } else if (blockIdx.x < 577){
    int idx = (blockIdx.x-65)*256 + threadIdx.x;   // over 131072
    int row = idx >> 9;
    int ii  = idx & 511;
    c1wT[idx] = c1w[(size_t)ii*256 + row];
  }
}

// ---------------------------------------------------------------------------
// K1b: Kmax[bh] = max_j ||k_j||_2 (softmax shift bound).
__global__ __launch_bounds__(256) void k_kmax(
    const float2* __restrict__ kvT, float* __restrict__ Kmax){
  int bh = blockIdx.x; int tid = threadIdx.x;
  const float2* base = kvT + (size_t)bh*16*1024;
  float mx = 0.f;
#pragma unroll
  for(int r=0;r<4;++r){
    int j = tid + 256*r;
    float ss = 0.f;
#pragma unroll
    for(int c=0;c<16;++c){ float2 kv = base[c*1024 + j]; ss += kv.x*kv.x; }
    mx = fmaxf(mx, ss);
  }
  mx = wmax64(mx);
  __shared__ float red[4];
  int lane = tid&63, wv = tid>>6;
  if(lane==0) red[wv]=mx;
  __syncthreads();
  if(tid==0) Kmax[bh] = sqrtf(fmaxf(fmaxf(red[0],red[1]),fmaxf(red[2],red[3])));
}

// ---------------------------------------------------------------------------
// K2: attention (R10 plateau version — 238us measured, no spill).
// Bound-shift softmax (exact). Gc via inverse dist map. Main loop
// barrier-free: 16 float2 kv loads, 32 QK fma, 2 exp, 32 PV fma.
__global__ __launch_bounds__(256, 3) void k_attn(
    const float* __restrict__ qb, const float2* __restrict__ kvT,
    const int* __restrict__ dmask, const float* __restrict__ relT,
    const float* __restrict__ Kmax, float* __restrict__ attn_raw){
  int tid = threadIdx.x;
  int lane = tid & 63, wv = tid >> 6;       // wave 0..3
  int bh  = blockIdx.y;                     // 0..31
  int i0  = blockIdx.x*8;                   // grid.x = 128
  int b = bh >> 2, h = bh & 3;
  int r0 = wv*2, r1 = wv*2 + 1;

  __shared__ float Gc[8][1024];      // 32 KB; aliased as red[] in epilogue
  __shared__ float qs[8][16];
  __shared__ float G0s[8], G1024s[8];
  __shared__ float gmS[8];
  __shared__ float Ms[8];
  __shared__ float sums[8];

  if (tid < 128){
    int r = tid >> 4, c = tid & 15;
    qs[r][c] = qb[((size_t)bh*1024 + i0 + r)*16 + c] * 0.25f;
  }
  __syncthreads();

  // --- phase 1: interior Gc via inverse map (lane owns d) ---
#pragma unroll 1
  for(int bb=0; bb<5; ++bb){
    int d = tid + 256*bb;
    if (d <= 1024){
      float rl[16];
#pragma unroll
      for(int c=0;c<16;++c) rl[c] = relT[c*1025 + d];
#pragma unroll
      for(int r=0;r<8;++r){
        float g = 0.f;
#pragma unroll
        for(int c=0;c<16;++c) g += qs[r][c]*rl[c];
        if (d == 0)        G0s[r] = g;
        else if (d == 1024) G1024s[r] = g;
        else {
          int j = i0 + r + 512 - d;
          if (j >= 0 && j < 1024) Gc[r][j] = g;
        }
      }
    }
  }
  __syncthreads();
  // --- phase 2: clip-plateau tails ---
#pragma unroll
  for(int r=0;r<8;++r){
    float g0 = G0s[r], g1 = G1024s[r];
    int lo = i0 + r - 512;     // j <= lo  -> dist clipped high (d=1024)
    int hi = i0 + r + 512;     // j >= hi  -> dist clipped low  (d=0)
#pragma unroll
    for(int p=0;p<4;++p){
      int j = tid + 256*p;
      if (j >= hi) Gc[r][j] = g0;
      else if (j <= lo) Gc[r][j] = g1;
    }
  }
  __syncthreads();
  // --- phase 3: row max of Gc ---
  {
    int r = tid >> 5, jb = tid & 31;
    float gm = -3.0e38f;
#pragma unroll
    for(int k=0;k<32;++k) gm = fmaxf(gm, Gc[r][jb + 32*k]);
#pragma unroll
    for(int m=1;m<32;m<<=1) gm = fmaxf(gm, __shfl_xor(gm, m, 64));
    if ((lane&31)==0) gmS[r] = gm;
  }
  __syncthreads();
  if (tid < 8){
    float qn = 0.f;
#pragma unroll
    for(int c=0;c<16;++c) qn += qs[tid][c]*qs[tid][c];
    Ms[tid] = gmS[tid] + sqrtf(qn)*Kmax[bh];
  }
  __syncthreads();

  float q0[16], q1[16];
#pragma unroll
  for(int c=0;c<16;++c){ q0[c]=qs[r0][c]; q1[c]=qs[r1][c]; }
  float M0 = Ms[r0], M1 = Ms[r1];

  const float2* kvb = kvT + (size_t)bh*16*1024;
  const int* mb0 = dmask + ((size_t)bh*1024 + i0 + r0)*1024;
  const int* mb1 = dmask + ((size_t)bh*1024 + i0 + r1)*1024;

  float s0=0.f, s1=0.f;
  float a0[16], a1[16];
#pragma unroll
  for(int c=0;c<16;++c){ a0[c]=0.f; a1[c]=0.f; }

#pragma unroll 1
  for(int t=0;t<16;++t){
    int j = lane + 64*t;
    int mk0 = mb0[j], mk1 = mb1[j];
    float2 kv[16];
#pragma unroll
    for(int c=0;c<16;++c) kv[c] = kvb[c*1024 + j];
    float sv0 = Gc[r0][j], sv1 = Gc[r1][j];
#pragma unroll
    for(int c=0;c<16;++c){ sv0 += q0[c]*kv[c].x; sv1 += q1[c]*kv[c].x; }
    float p0 = mk0 ? 0.f : __expf(sv0 - M0);
    float p1 = mk1 ? 0.f : __expf(sv1 - M1);
    s0 += p0; s1 += p1;
#pragma unroll
    for(int c=0;c<16;++c){ a0[c] += p0*kv[c].y; a1[c] += p1*kv[c].y; }
  }
  // uniform shift per row -> plain reductions
  s0 = wsum64(s0); s1 = wsum64(s1);
#pragma unroll
  for(int c=0;c<16;++c){
    float x0 = a0[c];
    x0 += __shfl_xor(x0, 32, 64); x0 += __shfl_xor(x0, 16, 64);
    a0[c] = x0;
    float x1 = a1[c];
    x1 += __shfl_xor(x1, 32, 64); x1 += __shfl_xor(x1, 16, 64);
    a1[c] = x1;
  }
  __syncthreads();            // all waves done with Gc -> safe to alias
  float* red = &Gc[0][0];     // red[row*272 + g*17 + c]
  if (lane < 16){
#pragma unroll
    for(int c=0;c<16;++c){
      red[r0*272 + lane*17 + c] = a0[c];
      red[r1*272 + lane*17 + c] = a1[c];
    }
  }
  if (lane == 0){ sums[r0] = s0; sums[r1] = s1; }
  __syncthreads();
  if (tid < 128){
    int row = tid >> 4, c = tid & 15;
    float tot = 0.f;
#pragma unroll
    for(int g=0; g<16; ++g) tot += red[row*272 + g*17 + c];
    attn_raw[((size_t)b*1024 + i0 + row)*64 + h*16 + c] = tot / sums[row];
  }
}

// ---------------------------------------------------------------------------
// K3: Wo proj + double residual + LN2 + W_in. 16 tokens/block (grid 512).
// Stage 1: wave-per-token LN+Wo (Wo is 16KB -> L1-resident across re-reads).
// Stage 2: WEIGHT-STATIONARY W_in: thread owns column oc, holds W_in[:,oc]
// in 64 regs (read once per block: 33 MB total vs 655 MB streaming).
__global__ __launch_bounds__(256) void k_post_attn(
    const float* __restrict__ x, const float* __restrict__ attn_raw,
    const float* __restrict__ Wo, const float* __restrict__ bo,
    const float* __restrict__ ln2w, const float* __restrict__ ln2b,
    const float* __restrict__ W_in,
    float* __restrict__ x2, float* __restrict__ u0, float* __restrict__ zsarr){
  int tid = threadIdx.x;
  int lane = tid & 63, wv = tid >> 6;
  int tok0 = blockIdx.x * 16;          // grid 512
  __shared__ float arS[16][64];
  __shared__ float lnS[16][64];
  for(int l = tid; l < 1024; l += 256)
    arS[l >> 6][l & 63] = attn_raw[(size_t)tok0*64 + l];
  __syncthreads();
  // wave wv handles tokens wv*4 .. wv*4+3
#pragma unroll 1
  for(int tt = 0; tt < 4; ++tt){
    int tl = wv*4 + tt;
    int token = tok0 + tl;
    float acc = bo[lane];
#pragma unroll 4
    for(int dd = 0; dd < 64; ++dd) acc += arS[tl][dd] * Wo[dd*64 + lane];
    float t = 2.f*x[(size_t)token*64 + lane] + acc;   // x + (attn_out + x)
    x2[(size_t)token*64 + lane] = t;
    float mean = wsum64(t)*0.015625f;
    float dlt = t - mean;
    float var = wsum64(dlt*dlt)*0.015625f;
    lnS[tl][lane] = dlt*rsqrtf(var+1e-5f)*ln2w[lane] + ln2b[lane];
  }
  __syncthreads();
  // stage 2: weight-stationary W_in
  int oc = tid;
  float w[64];
#pragma unroll
  for(int dd = 0; dd < 64; ++dd) w[dd] = W_in[dd*256 + oc];
  const float4* lnS4 = (const float4*)&lnS[0][0];
#pragma unroll 1
  for(int tl = 0; tl < 16; ++tl){
    float acc = 0.f;
#pragma unroll
    for(int d4 = 0; d4 < 16; ++d4){
      float4 l4 = lnS4[tl*16 + d4];
      acc += l4.x*w[4*d4] + l4.y*w[4*d4+1] + l4.z*w[4*d4+2] + l4.w*w[4*d4+3];
    }
    int token = tok0 + tl;
    if (oc < 128) u0[(size_t)token*128 + oc] = acc;
    else          zsarr[(size_t)token*128 + (oc-128)] = silu_f(acc);
  }
}

// ---------------------------------------------------------------------------
// K4: causal depthwise conv4 + silu + x-proj(132) + softplus dt. 128 lanes/token.
__global__ __launch_bounds__(256) void k_conv_proj(
    const float* __restrict__ u0, const float* __restrict__ conv_w, const float* __restrict__ conv_b,
    const float* __restrict__ W_xproj, const float* __restrict__ W_dt, const float* __restrict__ b_dt,
    float* __restrict__ uarr, float* __restrict__ Bmp, float* __restrict__ Cmp, float* __restrict__ dtarr){
  int sub = threadIdx.x >> 7, c = threadIdx.x & 127;
  int token = blockIdx.x*2 + sub;
  int b = token >> 10, i = token & 1023;
  __shared__ float us[2][128];
  __shared__ float dtin[2][4];
  float acc = conv_b[c];
#pragma unroll
  for(int k2=0;k2<4;++k2){
    int t2 = i - 3 + k2;
    if (t2 >= 0) acc += u0[((size_t)b*1024 + t2)*128 + c]*conv_w[c*4+k2];
  }
  float uv = silu_f(acc);
  uarr[(size_t)token*128 + c] = uv;
  us[sub][c] = uv;
  __syncthreads();
  float accA = 0.f, accB = 0.f;
  int cB = 128 + (c & 3);
#pragma unroll 4
  for(int dd=0; dd<128; ++dd){
    float xd = us[sub][dd];
    accA += xd * W_xproj[dd*132 + c];
    accB += xd * W_xproj[dd*132 + cB];
  }
  if (c < 4){ dtin[sub][c] = accA; Cmp[(size_t)token*64 + 60 + c] = accB; }
  else if (c < 68) Bmp[(size_t)token*64 + (c-4)] = accA;
  else             Cmp[(size_t)token*64 + (c-68)] = accA;
  __syncthreads();
  float dv = b_dt[c];
#pragma unroll
  for(int r2=0;r2<4;++r2) dv += dtin[sub][r2]*W_dt[r2*128 + c];
  dv = fmaxf(dv, 0.f) + log1pf(expf(-fabsf(dv)));   // softplus, stable
  dtarr[(size_t)token*128 + c] = dv;
}

// ---------------------------------------------------------------------------
// K5a: chunked scan phase A. wave = (b,d,chunk); lane = s. Per-chunk
// P = exp(A*sum dt) and R (zero-start response). 8192 waves -> 8/SIMD.
__global__ __launch_bounds__(256) void k_scan_a(
    const float* __restrict__ dtarr, const float* __restrict__ uarr,
    const float* __restrict__ Bmp, const float* __restrict__ A_log,
    float* __restrict__ Parr, float* __restrict__ Rarr){
  int lane = threadIdx.x & 63, warp = threadIdx.x >> 6;
  int w = blockIdx.x*4 + warp;          // 0..8191
  int c = w & 7, d = (w >> 3) & 127, b = w >> 10;
  float A = -expf(A_log[d*64 + lane]);
  int tb = c*128;
  const float* dtp = dtarr + ((size_t)b*1024 + tb)*128 + d;
  const float* up  = uarr  + ((size_t)b*1024 + tb)*128 + d;
  const float* Bp  = Bmp   + ((size_t)b*1024 + tb)*64 + lane;
  float R = 0.f, sdt = 0.f;
  for(int t0=0; t0<128; t0+=8){
    float dtc[8], uc[8], Bc[8];
#pragma unroll
    for(int r=0;r<8;++r){
      dtc[r]=dtp[(size_t)(t0+r)*128]; uc[r]=up[(size_t)(t0+r)*128]; Bc[r]=Bp[(size_t)(t0+r)*64];
    }
#pragma unroll
    for(int r=0;r<8;++r){
      float dt = dtc[r];
      R = R*__expf(dt*A) + dt*uc[r]*Bc[r];
      sdt += dt;
    }
  }
  Parr[(size_t)w*64 + lane] = __expf(sdt*A);
  Rarr[(size_t)w*64 + lane] = R;
}

// ---------------------------------------------------------------------------
// K5b: chunked scan phase C. Compose h_start from prior chunk summaries,
// then replay chunk emitting y (8 ILP wave reductions).
__global__ __launch_bounds__(256) void k_scan_c(
    const float* __restrict__ dtarr, const float* __restrict__ uarr,
    const float* __restrict__ Bmp, const float* __restrict__ Cmp,
    const float* __restrict__ zsarr, const float* __restrict__ A_log,
    const float* __restrict__ Dm, const float* __restrict__ Parr,
    const float* __restrict__ Rarr, float* __restrict__ ymp){
  int lane = threadIdx.x & 63, warp = threadIdx.x >> 6;
  int w = blockIdx.x*4 + warp;          // 0..8191
  int c = w & 7, d = (w >> 3) & 127, b = w >> 10;
  float A = -expf(A_log[d*64 + lane]);
  float Dv = Dm[d];
  float h = 0.f;
  int wbase = w - c;
#pragma unroll 1
  for(int cp=0; cp<c; ++cp){
    float P = Parr[(size_t)(wbase+cp)*64 + lane];
    float R = Rarr[(size_t)(wbase+cp)*64 + lane];
    h = h*P + R;
  }
  int tb = c*128;
  const float* dtp = dtarr + ((size_t)b*1024 + tb)*128 + d;
  const float* up  = uarr  + ((size_t)b*1024 + tb)*128 + d;
  const float* zp  = zsarr + ((size_t)b*1024 + tb)*128 + d;
  const float* Bp  = Bmp   + ((size_t)b*1024 + tb)*64 + lane;
  const float* Cp  = Cmp   + ((size_t)b*1024 + tb)*64 + lane;
  float* yp        = ymp   + ((size_t)b*1024 + tb)*128 + d;
  for(int t0=0; t0<128; t0+=8){
    float dtc[8], uc[8], Bc[8], Cc[8], zc[8];
#pragma unroll
    for(int r=0;r<8;++r){
      dtc[r]=dtp[(size_t)(t0+r)*128]; uc[r]=up[(size_t)(t0+r)*128];
      Bc[r]=Bp[(size_t)(t0+r)*64];    Cc[r]=Cp[(size_t)(t0+r)*64];
      zc[r]=zp[(size_t)(t0+r)*128];
    }
    float hc[8];
#pragma unroll
    for(int r=0;r<8;++r){
      float dt = dtc[r];
      h = h*__expf(dt*A) + dt*uc[r]*Bc[r];
      hc[r] = h*Cc[r];
    }
    float y[8];
#pragma unroll
    for(int r=0;r<8;++r) y[r] = wsum64(hc[r]);
    if (lane==0){
#pragma unroll
      for(int r=0;r<8;++r) yp[(size_t)(t0+r)*128] = (y[r] + uc[r]*Dv)*zc[r];
    }
  }
}

// ---------------------------------------------------------------------------
// K6: y @ W_out + leaky + group(4)-RMS-norm. wave per token.
__global__ __launch_bounds__(256) void k_wout(
    const float* __restrict__ ymp, const float* __restrict__ W_out,
    const float* __restrict__ gamma, float* __restrict__ marr){
  int lane = threadIdx.x & 63, warp = threadIdx.x >> 6;
  int token = blockIdx.x*4 + warp;
  __shared__ float ys[4][128];
  ys[warp][lane]      = ymp[(size_t)token*128 + lane];
  ys[warp][lane+64]   = ymp[(size_t)token*128 + 64 + lane];
  __syncthreads();
  float acc = 0.f;
#pragma unroll 4
  for(int dd=0; dd<128; ++dd) acc += ys[warp][dd]*W_out[dd*64 + lane];
  acc = acc >= 0.f ? acc : 0.01f*acc;                 // leaky relu
  float ss = acc*acc;
#pragma unroll
  for(int m=1;m<16;m<<=1) ss += __shfl_xor(ss, m, 64); // 16-lane group sum
  float rms = sqrtf(ss)*0.25f;                         // * dpg^-0.5 (dpg=16)
  marr[(size_t)token*64 + lane] = acc/(rms + 1e-5f)*gamma[lane];
}

// ---------------------------------------------------------------------------
// K7: GLU conv1 -> h2[b, tau(0..1026), i(0..255)], tau-major. Weights read
// from c1wT (lane-contiguous dwords).
__global__ __launch_bounds__(256) void k_h2(
    const float* __restrict__ marr, const float* __restrict__ c1wT,
    const float* __restrict__ c1b, float* __restrict__ h2){
  int b = blockIdx.y;
  int t0 = blockIdx.x * 16;
  int tid = threadIdx.x;
  __shared__ float ms[19][64];
  for(int l = tid; l < 19*64; l += 256){
    int row = l >> 6, cc = l & 63;
    int t = t0 - 3 + row;
    ms[row][cc] = (t >= 0 && t < 1024) ? marr[((size_t)b*1024 + t)*64 + cc] : 0.f;
  }
  __syncthreads();
  int i = tid;
  float acc1[16], acc2[16];
#pragma unroll
  for(int tl=0;tl<16;++tl){ acc1[tl]=0.f; acc2[tl]=0.f; }
  for(int cc=0; cc<64; ++cc){
    float mv[19];
#pragma unroll
    for(int r2=0;r2<19;++r2) mv[r2] = ms[r2][cc];
    const float* wr = c1wT + (size_t)cc*4*512;
    float wa0 = wr[      i], wa1 = wr[ 512+i], wa2 = wr[1024+i], wa3 = wr[1536+i];
    float wg0 = wr[  256+i], wg1 = wr[ 768+i], wg2 = wr[1280+i], wg3 = wr[1792+i];
#pragma unroll
    for(int tl=0; tl<16; ++tl){
      acc1[tl] += wa0*mv[tl+0] + wa1*mv[tl+1] + wa2*mv[tl+2] + wa3*mv[tl+3];
      acc2[tl] += wg0*mv[tl+0] + wg1*mv[tl+1] + wg2*mv[tl+2] + wg3*mv[tl+3];
    }
  }
  float bb1 = c1b[i], bb2 = c1b[i+256];
#pragma unroll
  for(int tl=0; tl<16; ++tl){
    int t = t0 + tl;
    if (t < 1027){
      float o1 = acc1[tl] + bb1;
      float o2 = acc2[tl] + bb2;
      h2[((size_t)b*1027 + t)*256 + i] = o1 * silu_f(o2);
    }
  }
}

// ---------------------------------------------------------------------------
// K8: conv2 (flipped d1_w) + 0.5*ff + residuals + LN3 -> out.
// 16 tokens per block: d1w streamed ONCE per block (256KB).
__global__ __launch_bounds__(256) void k_ff_final(
    const float* __restrict__ h2, const float* __restrict__ d1w, const float* __restrict__ d1b,
    const float* __restrict__ x2, const float* __restrict__ marr,
    const float* __restrict__ ln3w, const float* __restrict__ ln3b,
    float* __restrict__ out){
  int b = blockIdx.y;
  int s0 = blockIdx.x * 16;      // grid.x = 64
  int tid = threadIdx.x;
  int o = tid & 63, sg = tid >> 6;
  __shared__ float hs[19][256];
  for(int l = tid; l < 19*256; l += 256){
    int row = l >> 8, cc = l & 255;
    hs[row][cc] = h2[((size_t)b*1027 + s0 + row)*256 + cc];
  }
  __syncthreads();
  int sl = sg*4;
  float acc0=0.f, acc1=0.f, acc2=0.f, acc3=0.f;
  const float4* wb = (const float4*)d1w + o;   // d1w[i][o][0..3], lane-contig
#pragma unroll 2
  for(int i2=0; i2<256; ++i2){
    float4 wv = wb[(size_t)i2*64];
    float h0=hs[sl+0][i2], h1=hs[sl+1][i2], h2v=hs[sl+2][i2], h3=hs[sl+3][i2];
    float h4=hs[sl+4][i2], h5=hs[sl+5][i2], h6=hs[sl+6][i2];
    acc0 += h0*wv.w + h1*wv.z + h2v*wv.y + h3*wv.x;
    acc1 += h1*wv.w + h2v*wv.z + h3*wv.y + h4*wv.x;
    acc2 += h2v*wv.w + h3*wv.z + h4*wv.y + h5*wv.x;
    acc3 += h3*wv.w + h4*wv.z + h5*wv.y + h6*wv.x;
  }
  float accs[4] = {acc0, acc1, acc2, acc3};
  float bo_ = d1b[o];
#pragma unroll
  for(int r=0;r<4;++r){
    int s = s0 + sl + r;
    size_t idx = ((size_t)b*1024 + s)*64 + o;
    float tot = x2[idx] + marr[idx] + 0.5f*(accs[r] + bo_);
    float mean = wsum64(tot)*0.015625f;
    float dlt = tot - mean;
    float var = wsum64(dlt*dlt)*0.015625f;
    out[idx] = dlt*rsqrtf(var+1e-5f)*ln3w[o] + ln3b[o];
  }
}

// ---------------------------------------------------------------------------
extern "C" void kernel_launch(void* const* d_in, const int* in_sizes, int n_in,
                              void* d_out, int out_size, void* d_ws, size_t ws_size,
                              hipStream_t stream){
  const float* x       = (const float*)d_in[0];
  const int*   dmask   = (const int*)  d_in[1];   // bool -> int32 per harness
  const float* ln1w    = (const float*)d_in[2];
  const float* ln1b    = (const float*)d_in[3];
  const float* Wq      = (const float*)d_in[4];
  const float* Wkv     = (const float*)d_in[5];
  const float* Wo      = (const float*)d_in[6];
  const float* bo      = (const float*)d_in[7];
  const float* rel     = (const float*)d_in[8];
  const float* ln2w    = (const float*)d_in[9];
  const float* ln2b    = (const float*)d_in[10];
  const float* W_in    = (const float*)d_in[11];
  const float* conv_w  = (const float*)d_in[12];
  const float* conv_b  = (const float*)d_in[13];
  const float* W_xproj = (const float*)d_in[14];
  const float* W_dt    = (const float*)d_in[15];
  const float* b_dt    = (const float*)d_in[16];
  const float* A_log   = (const float*)d_in[17];
  const float* Dm      = (const float*)d_in[18];
  const float* W_out   = (const float*)d_in[19];
  const float* gamma   = (const float*)d_in[20];
  const float* c1w     = (const float*)d_in[21];
  const float* c1b     = (const float*)d_in[22];
  const float* d1w     = (const float*)d_in[23];
  const float* d1b     = (const float*)d_in[24];
  const float* ln3w    = (const float*)d_in[25];
  const float* ln3b    = (const float*)d_in[26];
  float* outp = (float*)d_out;

  float* ws = (float*)d_ws;
  float* qb       = ws;              // 524288
  float* kvT      = qb      + 524288;   // 1048576 floats (float2 view)
  float* attn_raw = kvT     + 1048576;  // 524288
  float* x2       = attn_raw+ 524288;
  float* u0       = x2      + 524288;   // 1048576
  float* zsarr    = u0      + 1048576;
  float* uarr     = zsarr   + 1048576;
  float* dtarr    = uarr    + 1048576;
  float* Bmp      = dtarr   + 1048576;  // 524288
  float* Cmp      = Bmp     + 524288;
  float* ymp      = Cmp     + 524288;   // 1048576
  float* marr     = ymp     + 1048576;  // 524288
  float* h2       = marr    + 524288;   // 2103296
  float* relT     = h2      + 2103296;  // 16400
  float* c1wT     = relT    + 16400;    // 131072
  float* Parr     = c1wT    + 131072;   // 524288
  float* Rarr     = Parr    + 524288;   // 524288
  float* Kmaxa    = Rarr    + 524288;   // 32

  k_ln1_qkv  <<<2048, 256, 0, stream>>>(x, ln1w, ln1b, Wq, Wkv, rel, c1w,
                                        qb, (float2*)kvT, relT, c1wT);
  k_kmax     <<<32, 256, 0, stream>>>((const float2*)kvT, Kmaxa);
  k_attn     <<<dim3(128,32), 256, 0, stream>>>(qb, (const float2*)kvT, dmask, relT, Kmaxa, attn_raw);
  k_post_attn<<<512, 256, 0, stream>>>(x, attn_raw, Wo, bo, ln2w, ln2b, W_in, x2, u0, zsarr);
  k_conv_proj<<<4096, 256, 0, stream>>>(u0, conv_w, conv_b, W_xproj, W_dt, b_dt, uarr, Bmp, Cmp, dtarr);
  k_scan_a   <<<2048, 256, 0, stream>>>(dtarr, uarr, Bmp, A_log, Parr, Rarr);
  k_scan_c   <<<2048, 256, 0, stream>>>(dtarr, uarr, Bmp, Cmp, zsarr, A_log, Dm, Parr, Rarr, ymp);
  k_wout     <<<2048, 256, 0, stream>>>(ymp, W_out, gamma, marr);
  k_h2       <<<dim3(65,8), 256, 0, stream>>>(marr, c1wT, c1b, h2);
  k_ff_final <<<dim3(64,8), 256, 0, stream>>>(h2, d1w, d1b, x2, marr, ln3w, ln3b, outp);
}